// Round 14
// baseline (132.899 us; speedup 1.0000x reference)
//
#include <hip/hip_runtime.h>
#include <math.h>

#define T_LEN 4096
#define M_LEN 2048   // complex length after real-packing
#define V_DIM 32
#define B_DIM 128
#define NTHREADS 512
#define NWAVES 8
#define NSERIES 4096          // B_DIM * V_DIM
#define FS NSERIES            // feats stride: feature-major [f][sid]

// LDS bank swizzle on float2 index: XOR bits 4-6 into bits 1-3.
// Preserves bit 0 -> even/odd f2 pairs stay adjacent (b128-safe, 16B aligned).
__device__ __forceinline__ int SW(int i) { return i ^ (((i >> 4) & 7) << 1); }

// storage position of frequency k after DIF [radix-4 x5, radix-2] (digit reversal)
__device__ __forceinline__ int fpos(int k) {
    return ((k & 3) << 9) | (((k >> 2) & 3) << 7) | (((k >> 4) & 3) << 5)
         | (((k >> 6) & 3) << 3) | (((k >> 8) & 3) << 1) | ((k >> 10) & 1);
}

// insert m into descending triple (a0 >= a1 >= a2)
__device__ __forceinline__ void ins3(float& a0, float& a1, float& a2, float m) {
    if (m > a0) { a2 = a1; a1 = a0; a0 = m; }
    else if (m > a1) { a2 = a1; a1 = m; }
    else if (m > a2) { a2 = m; }
}

// scr float regions
#define SCR_A_PART 0     // 8 waves x 6
#define SCR_A_FIN  48    // 6: [sum0,sum1,mn0,mn1,mx0,mx1]
#define SCR_B_PART 64    // 2 series x 8 waves x 4 lanes x 10
#define SCR_B_FIN  704   // 2 x 10
#define SCR_C_PART 724   // 8 waves x 6
#define SCR_SIZE   772

// radix-4 DIF stage, in place, swizzled addressing. W = e^{-2pi i/2048}.
// sincos hoisted out of the si loop (j identical for both series).
template <int ST>
__device__ __forceinline__ void fft_stage(float2* Z, int tid) {
    constexpr int lq = 9 - 2 * ST;           // log2(quarter)
    constexpr int q  = 1 << lq;
    const float scale = -3.06796158e-3f * (float)(1 << (2 * ST)); // -2pi/2048 * 4^ST
    const int g = tid >> lq;
    const int j = tid & (q - 1);
    float sn, cs;
    __sincosf(scale * (float)j, &sn, &cs);
    const float c2 = cs * cs - sn * sn, s2 = 2.f * cs * sn;     // W^2j
    const float c3 = c2 * cs - s2 * sn, s3 = c2 * sn + s2 * cs; // W^3j
    #pragma unroll
    for (int si = 0; si < 2; si++) {
        const int base = (si << 11) + (g << (lq + 2)) + j;
        const int p0 = SW(base), p1 = SW(base + q);
        const int p2i = SW(base + 2 * q), p3 = SW(base + 3 * q);
        float2 a = Z[p0], bb = Z[p1], c = Z[p2i], d = Z[p3];
        float t0r = a.x + c.x,  t0i = a.y + c.y;
        float t1r = a.x - c.x,  t1i = a.y - c.y;
        float t2r = bb.x + d.x, t2i = bb.y + d.y;
        float t3r = bb.x - d.x, t3i = bb.y - d.y;
        float y1r = t1r + t3i, y1i = t1i - t3r;
        float y2r = t0r - t2r, y2i = t0i - t2i;
        float y3r = t1r - t3i, y3i = t1i + t3r;
        Z[p0]  = make_float2(t0r + t2r, t0i + t2i);
        Z[p1]  = make_float2(y1r * cs - y1i * sn, y1r * sn + y1i * cs);
        Z[p2i] = make_float2(y2r * c2 - y2i * s2, y2r * s2 + y2i * c2);
        Z[p3]  = make_float2(y3r * c3 - y3i * s3, y3r * s3 + y3i * c3);
    }
}

// post-radix2 value at logical position p (radix-2 stage fused: pair add/sub)
__device__ __forceinline__ float2 rdpost(const float2* Z, int zb, int p) {
    int e = p & ~1;
    float4 v = *reinterpret_cast<const float4*>(&Z[zb + SW(e)]);
    return (p & 1) ? make_float2(v.x - v.z, v.y - v.w)
                   : make_float2(v.x + v.z, v.y + v.w);
}

__global__ __launch_bounds__(NTHREADS, 8)   // empirical best: max waves (VGPR cap 32)
void ts_feat_kernel(const float* __restrict__ x, float* __restrict__ feats) {
    __shared__ __align__(16) float data[2][T_LEN];   // 32 KB swizzled packed-complex
    __shared__ float scr[SCR_SIZE];
    float* const fd = &data[0][0];
    float2* const Z = reinterpret_cast<float2*>(fd);

    const int tid = threadIdx.x;
    // XCD-aware swizzle: all 16 v-pairs of batch b land on XCD b%8.
    const int bid  = blockIdx.x;           // 0..2047
    const int xcd  = bid & 7;
    const int idx  = bid >> 3;
    const int b    = xcd + ((idx >> 4) << 3);
    const int pair = idx & 15;
    const int v0   = pair * 2;
    const int sid0 = b * V_DIM + v0;

    const float2* __restrict__ p2 =
        reinterpret_cast<const float2*>(x + (size_t)b * T_LEN * V_DIM + v0);

    // ---------- sweep 1: load + sum/min/max; store swizzled ----------
    float s0 = 0.f, s1 = 0.f;
    float mn0 = 3.4e38f, mn1 = 3.4e38f, mx0 = -3.4e38f, mx1 = -3.4e38f;
    const int comp = tid & 1;
    #pragma unroll
    for (int i = 0; i < 8; i++) {
        int t = tid + i * NTHREADS;
        float2 val = p2[(size_t)t * (V_DIM / 2)];
        int f = SW(t >> 1);
        fd[(f << 1) + comp] = val.x;
        fd[T_LEN + (f << 1) + comp] = val.y;
        s0 += val.x; s1 += val.y;
        mn0 = fminf(mn0, val.x); mn1 = fminf(mn1, val.y);
        mx0 = fmaxf(mx0, val.x); mx1 = fmaxf(mx1, val.y);
    }
    #pragma unroll
    for (int o = 32; o > 0; o >>= 1) {
        s0 += __shfl_down(s0, o); s1 += __shfl_down(s1, o);
        mn0 = fminf(mn0, __shfl_down(mn0, o)); mn1 = fminf(mn1, __shfl_down(mn1, o));
        mx0 = fmaxf(mx0, __shfl_down(mx0, o)); mx1 = fmaxf(mx1, __shfl_down(mx1, o));
    }
    const int lane = tid & 63, wv = tid >> 6;
    if (lane == 0) {
        float* p = &scr[SCR_A_PART + wv * 6];
        p[0] = s0; p[1] = s1; p[2] = mn0; p[3] = mn1; p[4] = mx0; p[5] = mx1;
    }
    __syncthreads();                                     // sync 1
    if (tid < 6) {
        float r = scr[SCR_A_PART + tid];
        #pragma unroll
        for (int w = 1; w < NWAVES; w++) {
            float v = scr[SCR_A_PART + w * 6 + tid];
            r = (tid < 2) ? (r + v) : ((tid < 4) ? fminf(r, v) : fmaxf(r, v));
        }
        scr[SCR_A_FIN + tid] = r;
    }
    __syncthreads();                                     // sync 2
    const float mean0 = scr[SCR_A_FIN + 0] * (1.f / T_LEN);
    const float mean1 = scr[SCR_A_FIN + 1] * (1.f / T_LEN);
    float fmn = 0.f, fmx = 0.f;
    if (tid < 2) { fmn = scr[SCR_A_FIN + 2 + tid]; fmx = scr[SCR_A_FIN + 4 + tid]; }

    // ---------- sweep 2: THREE low-register passes per series ----------
    #pragma unroll 1
    for (int si = 0; si < 2; si++) {
        const float m = si ? mean1 : mean0;
        const int fb = (si << 11) + (tid << 2);          // float2 base
        float* const part = &scr[SCR_B_PART + si * 320 + wv * 40];

        // ---- P1: central moments + slope (4 accs, streaming) ----
        {
            float b0 = 0.f, b1 = 0.f, b2 = 0.f, b3 = 0.f;
            const float tf0 = (float)(tid * 8) - 2047.5f;
            float4 q = *reinterpret_cast<const float4*>(&Z[SW(fb)]);
            float c, cc;
            c = q.x - m; cc = c * c; b0 += cc; b1 += cc * c; b2 += cc * cc; b3 += c * tf0;
            c = q.y - m; cc = c * c; b0 += cc; b1 += cc * c; b2 += cc * cc; b3 += c * (tf0 + 1.f);
            c = q.z - m; cc = c * c; b0 += cc; b1 += cc * c; b2 += cc * cc; b3 += c * (tf0 + 2.f);
            c = q.w - m; cc = c * c; b0 += cc; b1 += cc * c; b2 += cc * cc; b3 += c * (tf0 + 3.f);
            q = *reinterpret_cast<const float4*>(&Z[SW(fb + 2)]);
            c = q.x - m; cc = c * c; b0 += cc; b1 += cc * c; b2 += cc * cc; b3 += c * (tf0 + 4.f);
            c = q.y - m; cc = c * c; b0 += cc; b1 += cc * c; b2 += cc * cc; b3 += c * (tf0 + 5.f);
            c = q.z - m; cc = c * c; b0 += cc; b1 += cc * c; b2 += cc * cc; b3 += c * (tf0 + 6.f);
            c = q.w - m; cc = c * c; b0 += cc; b1 += cc * c; b2 += cc * cc; b3 += c * (tf0 + 7.f);
            #pragma unroll
            for (int o = 32; o >= 4; o >>= 1) {
                b0 += __shfl_down(b0, o); b1 += __shfl_down(b1, o);
                b2 += __shfl_down(b2, o); b3 += __shfl_down(b3, o);
            }
            if (lane < 4) {
                part[lane * 10 + 0] = b0; part[lane * 10 + 1] = b1;
                part[lane * 10 + 2] = b2; part[lane * 10 + 3] = b3;
            }
        }

        // ---- P2a: lags 1-3 (3 accs + 3-deep window) ----
        {
            float l1 = 0.f, l2 = 0.f, l3 = 0.f;
            float p1v = 0.f, p2v = 0.f, p3v = 0.f;
            if (tid > 0) {                               // x[8t-3..8t-1]
                float2 tv = Z[SW(fb - 2)];
                float2 tq = Z[SW(fb - 1)];
                p3v = tv.y - m; p2v = tq.x - m; p1v = tq.y - m;
            }
            float4 q = *reinterpret_cast<const float4*>(&Z[SW(fb)]);
            float c;
            #define STEP3(V) { c = (V) - m; \
                l1 += p1v * c; l2 += p2v * c; l3 += p3v * c; \
                p3v = p2v; p2v = p1v; p1v = c; }
            STEP3(q.x) STEP3(q.y) STEP3(q.z) STEP3(q.w)
            q = *reinterpret_cast<const float4*>(&Z[SW(fb + 2)]);
            STEP3(q.x) STEP3(q.y) STEP3(q.z) STEP3(q.w)
            #undef STEP3
            #pragma unroll
            for (int o = 32; o >= 4; o >>= 1) {
                l1 += __shfl_down(l1, o); l2 += __shfl_down(l2, o);
                l3 += __shfl_down(l3, o);
            }
            if (lane < 4) {
                part[lane * 10 + 4] = l1; part[lane * 10 + 5] = l2;
                part[lane * 10 + 6] = l3;
            }
        }

        // ---- P2b: lags 4-6 (3 accs + 6-deep window) ----
        {
            float l4 = 0.f, l5 = 0.f, l6 = 0.f;
            float p1v = 0.f, p2v = 0.f, p3v = 0.f, p4v = 0.f, p5v = 0.f, p6v = 0.f;
            if (tid > 0) {                               // x[8t-6..8t-1]
                float2 tv = Z[SW(fb - 3)];
                float4 tq = *reinterpret_cast<const float4*>(&Z[SW(fb - 2)]);
                p6v = tv.x - m; p5v = tv.y - m;
                p4v = tq.x - m; p3v = tq.y - m; p2v = tq.z - m; p1v = tq.w - m;
            }
            float4 q = *reinterpret_cast<const float4*>(&Z[SW(fb)]);
            float c;
            #define STEP6(V) { c = (V) - m; \
                l4 += p4v * c; l5 += p5v * c; l6 += p6v * c; \
                p6v = p5v; p5v = p4v; p4v = p3v; p3v = p2v; p2v = p1v; p1v = c; }
            STEP6(q.x) STEP6(q.y) STEP6(q.z) STEP6(q.w)
            q = *reinterpret_cast<const float4*>(&Z[SW(fb + 2)]);
            STEP6(q.x) STEP6(q.y) STEP6(q.z) STEP6(q.w)
            #undef STEP6
            #pragma unroll
            for (int o = 32; o >= 4; o >>= 1) {
                l4 += __shfl_down(l4, o); l5 += __shfl_down(l5, o);
                l6 += __shfl_down(l6, o);
            }
            if (lane < 4) {
                part[lane * 10 + 7] = l4; part[lane * 10 + 8] = l5;
                part[lane * 10 + 9] = l6;
            }
        }
    }
    __syncthreads();                                     // sync 3

    // ---------- B finalize overlapped with FFT stage 0 ----------
    if (tid < 10) {
        float s = 0.f;
        #pragma unroll
        for (int e = 0; e < 32; e++) s += scr[SCR_B_PART + e * 10 + tid];
        scr[SCR_B_FIN + tid] = s;
    } else if (tid >= 16 && tid < 26) {
        const int f = tid - 16;
        float s = 0.f;
        #pragma unroll
        for (int e = 0; e < 32; e++) s += scr[SCR_B_PART + 320 + e * 10 + f];
        scr[SCR_B_FIN + 10 + f] = s;
    }
    fft_stage<0>(Z, tid);
    __syncthreads();                                     // sync 4

    // feats base features by tid 0/1 (feature-major layout), overlap FFT stage 1
    if (tid < 2) {
        const float* A = &scr[SCR_B_FIN + tid * 10];
        const float m = tid ? mean1 : mean0;
        float c2 = A[0], c3 = A[1], c4 = A[2], ct = A[3];
        float var = c2 * (1.f / T_LEN);
        float sd  = sqrtf(var + 1e-8f);
        float i3  = 1.f / (sd * sd * sd);
        float dn  = c2 + 1e-8f;
        float* fp = feats + (sid0 + tid);
        fp[0 * FS] = m; fp[1 * FS] = sd;
        fp[2 * FS] = c3 * (1.f / T_LEN) * i3;
        fp[3 * FS] = c4 * (1.f / T_LEN) * i3 / sd;
        fp[4 * FS] = fmn; fp[5 * FS] = fmx;
        fp[6 * FS] = ct / 5726622720.f;                  // sum(tc^2) = T(T^2-1)/12
        fp[10 * FS] = A[4] / dn; fp[11 * FS] = A[5] / dn; fp[12 * FS] = A[6] / dn;
        fp[13 * FS] = A[7] / dn; fp[14 * FS] = A[8] / dn; fp[15 * FS] = A[9] / dn;
    }
    fft_stage<1>(Z, tid);
    __syncthreads();                                     // sync 5
    fft_stage<2>(Z, tid);
    __syncthreads();                                     // sync 6
    fft_stage<3>(Z, tid);
    __syncthreads();                                     // sync 7
    fft_stage<4>(Z, tid);
    __syncthreads();                                     // sync 8

    // ---------- magnitudes, PER SERIES (3 live tops): conjugate pair once ----------
    // X_k = (Er+u, Ei+v), X_{2048-k} = (Er-u, v-Ei), u = cs*Or - sn*Oi, v = cs*Oi + sn*Or
    const float inv_T = 1.f / (float)T_LEN;
    #pragma unroll 1
    for (int si = 0; si < 2; si++) {
        const int zb = si << 11;
        float a0 = -1.f, a1 = -1.f, a2 = -1.f;
        #pragma unroll
        for (int i = 0; i < 2; i++) {
            int k  = 1 + tid + (i << 9);                 // 1..1024
            int pa = fpos(k);
            int pb = fpos(M_LEN - k);
            float ang = (float)k * (-3.14159265358979f / (float)M_LEN);
            float sn, cs; __sincosf(ang, &sn, &cs);
            float2 Za = rdpost(Z, zb, pa), Zb = rdpost(Z, zb, pb);
            float Er = 0.5f * (Za.x + Zb.x), Ei = 0.5f * (Za.y - Zb.y);
            float Or = 0.5f * (Za.y + Zb.y), Oi = 0.5f * (Zb.x - Za.x);
            float u = cs * Or - sn * Oi, v = cs * Oi + sn * Or;
            float Xr = Er + u, Xi = Ei + v;
            ins3(a0, a1, a2, sqrtf(Xr * Xr + Xi * Xi));
            if (k != 1024) {
                float Yr = Er - u, Yi = v - Ei;
                ins3(a0, a1, a2, sqrtf(Yr * Yr + Yi * Yi));
            }
        }
        if (tid == 0) {                                  // Nyquist k=2048
            float2 Z0 = rdpost(Z, zb, 0);
            ins3(a0, a1, a2, fabsf(Z0.x - Z0.y));
        }
        #pragma unroll
        for (int o = 32; o > 0; o >>= 1) {
            float u0 = __shfl_down(a0, o), u1 = __shfl_down(a1, o), u2 = __shfl_down(a2, o);
            ins3(a0, a1, a2, u0); ins3(a0, a1, a2, u1); ins3(a0, a1, a2, u2);
        }
        if (lane == 0) {
            float* p = &scr[SCR_C_PART + wv * 6 + si * 3];
            p[0] = a0; p[1] = a1; p[2] = a2;
        }
    }
    __syncthreads();                                     // sync 9
    if (tid < 2) {
        const int off = SCR_C_PART + tid * 3;
        float t0 = scr[off], t1 = scr[off + 1], t2 = scr[off + 2];
        #pragma unroll
        for (int w = 1; w < NWAVES; w++) {
            ins3(t0, t1, t2, scr[off + w * 6]);
            ins3(t0, t1, t2, scr[off + w * 6 + 1]);
            ins3(t0, t1, t2, scr[off + w * 6 + 2]);
        }
        float* fp = feats + (sid0 + tid);
        fp[7 * FS] = t0 * inv_T; fp[8 * FS] = t1 * inv_T; fp[9 * FS] = t2 * inv_T;
    }
}

// One 32-lane group per (b, f): coalesced 128-B read + shuffle reduce.
__global__ __launch_bounds__(256)
void ts_reduce_kernel(const float* __restrict__ feats, float* __restrict__ out) {
    const int tid = threadIdx.x;
    const int lane = tid & 63;
    const int wid = blockIdx.x * 4 + (tid >> 6);      // global wave 0..1023
    const int pairidx = wid * 2 + (lane >> 5);        // (b,f) pair 0..2047
    const int b = pairidx >> 4, f = pairidx & 15;
    const int v = lane & 31;
    float val = feats[f * FS + b * V_DIM + v];
    float s = val;
    #pragma unroll
    for (int o = 16; o > 0; o >>= 1) s += __shfl_xor(s, o);
    float m = s * (1.f / V_DIM);
    float d = val - m;
    float q = d * d;
    #pragma unroll
    for (int o = 16; o > 0; o >>= 1) q += __shfl_xor(q, o);
    float sd = sqrtf(q * (1.f / V_DIM));
    if (v == 0) {
        out[b * 32 + f]      = fminf(fmaxf(m,  -5.f), 5.f);
        out[b * 32 + 16 + f] = fminf(fmaxf(sd, -5.f), 5.f);
    }
}

extern "C" void kernel_launch(void* const* d_in, const int* in_sizes, int n_in,
                              void* d_out, int out_size, void* d_ws, size_t ws_size,
                              hipStream_t stream) {
    const float* x = (const float*)d_in[0];
    float* out = (float*)d_out;
    float* feats = (float*)d_ws;   // feature-major [16][4096] = 256 KB

    hipLaunchKernelGGL(ts_feat_kernel, dim3(B_DIM * V_DIM / 2), dim3(NTHREADS), 0, stream,
                       x, feats);
    hipLaunchKernelGGL(ts_reduce_kernel, dim3(256), dim3(256), 0, stream,
                       feats, out);
}

// Round 15
// 125.344 us; speedup vs baseline: 1.0603x; 1.0603x over previous
//
#include <hip/hip_runtime.h>
#include <math.h>

#define T_LEN 4096
#define M_LEN 2048   // complex length after real-packing
#define V_DIM 32
#define B_DIM 128
#define NTHREADS 256
#define NWAVES 4
#define NSERIES 4096          // B_DIM * V_DIM
#define FS NSERIES            // feats stride: feature-major [f][sid]

// LDS bank swizzle on float2 index: XOR bits 4-6 into bits 1-3.
// Preserves bit 0 -> even/odd f2 pairs stay adjacent (b128-safe, 16B aligned).
__device__ __forceinline__ int SW(int i) { return i ^ (((i >> 4) & 7) << 1); }

// storage position of frequency k after DIF [radix-4 x5, radix-2] (digit reversal)
__device__ __forceinline__ int fpos(int k) {
    return ((k & 3) << 9) | (((k >> 2) & 3) << 7) | (((k >> 4) & 3) << 5)
         | (((k >> 6) & 3) << 3) | (((k >> 8) & 3) << 1) | ((k >> 10) & 1);
}

// insert m into descending triple (a0 >= a1 >= a2)
__device__ __forceinline__ void ins3(float& a0, float& a1, float& a2, float m) {
    if (m > a0) { a2 = a1; a1 = a0; a0 = m; }
    else if (m > a1) { a2 = a1; a1 = m; }
    else if (m > a2) { a2 = m; }
}

// scr float regions (single series, 4 waves)
#define SCR_A_PART 0     // 4 waves x 3 [sum,mn,mx]
#define SCR_A_FIN  12    // 3
#define SCR_B_PART 16    // 4 waves x 4 lanes x 10
#define SCR_B_FIN  176   // 10
#define SCR_C_PART 186   // 4 waves x 3
#define SCR_SIZE   200

// radix-4 DIF stage, in place, swizzled addressing. W = e^{-2pi i/2048}.
template <int ST>
__device__ __forceinline__ void fft_stage(float2* Z, int tid) {
    constexpr int lq = 9 - 2 * ST;           // log2(quarter)
    constexpr int q  = 1 << lq;
    const float scale = -3.06796158e-3f * (float)(1 << (2 * ST)); // -2pi/2048 * 4^ST
    #pragma unroll
    for (int i = 0; i < 2; i++) {
        const int w = tid + (i << 8);        // 512 butterflies
        const int g = w >> lq;
        const int j = w & (q - 1);
        float sn, cs;
        __sincosf(scale * (float)j, &sn, &cs);
        const float c2 = cs * cs - sn * sn, s2 = 2.f * cs * sn;     // W^2j
        const float c3 = c2 * cs - s2 * sn, s3 = c2 * sn + s2 * cs; // W^3j
        const int base = (g << (lq + 2)) + j;
        const int p0 = SW(base), p1 = SW(base + q);
        const int p2i = SW(base + 2 * q), p3 = SW(base + 3 * q);
        float2 a = Z[p0], bb = Z[p1], c = Z[p2i], d = Z[p3];
        float t0r = a.x + c.x,  t0i = a.y + c.y;
        float t1r = a.x - c.x,  t1i = a.y - c.y;
        float t2r = bb.x + d.x, t2i = bb.y + d.y;
        float t3r = bb.x - d.x, t3i = bb.y - d.y;
        float y1r = t1r + t3i, y1i = t1i - t3r;
        float y2r = t0r - t2r, y2i = t0i - t2i;
        float y3r = t1r - t3i, y3i = t1i + t3r;
        Z[p0]  = make_float2(t0r + t2r, t0i + t2i);
        Z[p1]  = make_float2(y1r * cs - y1i * sn, y1r * sn + y1i * cs);
        Z[p2i] = make_float2(y2r * c2 - y2i * s2, y2r * s2 + y2i * c2);
        Z[p3]  = make_float2(y3r * c3 - y3i * s3, y3r * s3 + y3i * c3);
    }
}

// post-radix2 value at logical position p (radix-2 stage fused: pair add/sub)
__device__ __forceinline__ float2 rdpost(const float2* Z, int p) {
    int e = p & ~1;
    float4 v = *reinterpret_cast<const float4*>(&Z[SW(e)]);
    return (p & 1) ? make_float2(v.x - v.z, v.y - v.w)
                   : make_float2(v.x + v.z, v.y + v.w);
}

__global__ __launch_bounds__(NTHREADS, 8)   // 8 blocks/CU: 32 waves, VGPR cap 64
void ts_feat_kernel(const float* __restrict__ x, float* __restrict__ feats) {
    __shared__ __align__(16) float data[T_LEN];      // 16 KB swizzled packed-complex
    __shared__ float scr[SCR_SIZE];
    float2* const Z = reinterpret_cast<float2*>(&data[0]);

    const int tid = threadIdx.x;
    // XCD swizzle: all 32 v-blocks of batch b land on XCD b&7; bijective over 4096.
    const int bid = blockIdx.x;            // 0..4095
    const int xcd = bid & 7;
    const int idx = bid >> 3;              // 0..511
    const int b   = xcd + ((idx >> 5) << 3);    // batch 0..127
    const int v   = idx & 31;
    const int sid = b * V_DIM + v;

    const float* __restrict__ px = x + (size_t)b * T_LEN * V_DIM + v;

    // ---------- sweep 1: 16 scalar loads -> regs; sum/min/max; LDS store ----------
    float xr[16];
    #pragma unroll
    for (int u = 0; u < 16; u++) {
        xr[u] = px[(size_t)(16 * tid + u) * V_DIM];
    }
    float s = 0.f, mn = 3.4e38f, mx = -3.4e38f;
    #pragma unroll
    for (int u = 0; u < 16; u++) {
        s += xr[u]; mn = fminf(mn, xr[u]); mx = fmaxf(mx, xr[u]);
    }
    const int fb2 = tid * 8;               // first owned float2 index
    #pragma unroll
    for (int u4 = 0; u4 < 4; u4++) {
        float4 q = make_float4(xr[4 * u4], xr[4 * u4 + 1], xr[4 * u4 + 2], xr[4 * u4 + 3]);
        *reinterpret_cast<float4*>(&Z[SW(fb2 + 2 * u4)]) = q;
    }
    #pragma unroll
    for (int o = 32; o > 0; o >>= 1) {
        s += __shfl_down(s, o);
        mn = fminf(mn, __shfl_down(mn, o));
        mx = fmaxf(mx, __shfl_down(mx, o));
    }
    const int lane = tid & 63, wv = tid >> 6;
    if (lane == 0) {
        scr[SCR_A_PART + wv * 3 + 0] = s;
        scr[SCR_A_PART + wv * 3 + 1] = mn;
        scr[SCR_A_PART + wv * 3 + 2] = mx;
    }
    __syncthreads();                                     // sync 1
    if (tid < 3) {
        float r = scr[SCR_A_PART + tid];
        #pragma unroll
        for (int w = 1; w < NWAVES; w++) {
            float vv = scr[SCR_A_PART + w * 3 + tid];
            r = (tid == 0) ? (r + vv) : ((tid == 1) ? fminf(r, vv) : fmaxf(r, vv));
        }
        scr[SCR_A_FIN + tid] = r;
    }
    __syncthreads();                                     // sync 2
    const float m = scr[SCR_A_FIN + 0] * (1.f / T_LEN);

    // ---------- sweep 2: fused moments/slope/ACF from REGISTERS ----------
    {
        float q2 = 0.f, q3 = 0.f, q4 = 0.f, qt = 0.f;
        float l1 = 0.f, l2 = 0.f, l3 = 0.f, l4 = 0.f, l5 = 0.f, l6 = 0.f;
        float p1v = 0.f, p2v = 0.f, p3v = 0.f, p4v = 0.f, p5v = 0.f, p6v = 0.f;
        if (tid > 0) {                     // boundary: x[16t-6..16t-1] from LDS
            float2 tv = Z[SW(fb2 - 3)];
            float4 tq = *reinterpret_cast<const float4*>(&Z[SW(fb2 - 2)]);
            p6v = tv.x - m; p5v = tv.y - m;
            p4v = tq.x - m; p3v = tq.y - m; p2v = tq.z - m; p1v = tq.w - m;
        }
        const float tf0 = (float)(tid * 16) - 2047.5f;
        #pragma unroll
        for (int u = 0; u < 16; u++) {
            float c = xr[u] - m;
            float cc = c * c;
            q2 += cc; q3 += cc * c; q4 += cc * cc;
            qt += c * (tf0 + (float)u);
            l1 += p1v * c; l2 += p2v * c; l3 += p3v * c;
            l4 += p4v * c; l5 += p5v * c; l6 += p6v * c;
            p6v = p5v; p5v = p4v; p4v = p3v; p3v = p2v; p2v = p1v; p1v = c;
        }
        #pragma unroll
        for (int o = 32; o >= 4; o >>= 1) {
            q2 += __shfl_down(q2, o); q3 += __shfl_down(q3, o);
            q4 += __shfl_down(q4, o); qt += __shfl_down(qt, o);
            l1 += __shfl_down(l1, o); l2 += __shfl_down(l2, o);
            l3 += __shfl_down(l3, o); l4 += __shfl_down(l4, o);
            l5 += __shfl_down(l5, o); l6 += __shfl_down(l6, o);
        }
        if (lane < 4) {
            float* part = &scr[SCR_B_PART + wv * 40 + lane * 10];
            part[0] = q2; part[1] = q3; part[2] = q4; part[3] = qt;
            part[4] = l1; part[5] = l2; part[6] = l3;
            part[7] = l4; part[8] = l5; part[9] = l6;
        }
    }
    __syncthreads();                                     // sync 3

    // ---------- B finalize overlapped with FFT stage 0 ----------
    if (tid < 10) {
        float acc = 0.f;
        #pragma unroll
        for (int e = 0; e < 16; e++) acc += scr[SCR_B_PART + e * 10 + tid];
        scr[SCR_B_FIN + tid] = acc;
    }
    fft_stage<0>(Z, tid);
    __syncthreads();                                     // sync 4

    // feats base features by tid 0 (feature-major), overlap FFT stage 1
    if (tid == 0) {
        const float* A = &scr[SCR_B_FIN];
        float c2 = A[0], c3 = A[1], c4 = A[2], ct = A[3];
        float var = c2 * (1.f / T_LEN);
        float sd  = sqrtf(var + 1e-8f);
        float i3  = 1.f / (sd * sd * sd);
        float dn  = c2 + 1e-8f;
        float* fp = feats + sid;
        fp[0 * FS] = m; fp[1 * FS] = sd;
        fp[2 * FS] = c3 * (1.f / T_LEN) * i3;
        fp[3 * FS] = c4 * (1.f / T_LEN) * i3 / sd;
        fp[4 * FS] = scr[SCR_A_FIN + 1]; fp[5 * FS] = scr[SCR_A_FIN + 2];
        fp[6 * FS] = ct / 5726622720.f;                  // sum(tc^2) = T(T^2-1)/12
        fp[10 * FS] = A[4] / dn; fp[11 * FS] = A[5] / dn; fp[12 * FS] = A[6] / dn;
        fp[13 * FS] = A[7] / dn; fp[14 * FS] = A[8] / dn; fp[15 * FS] = A[9] / dn;
    }
    fft_stage<1>(Z, tid);
    __syncthreads();                                     // sync 5
    fft_stage<2>(Z, tid);
    __syncthreads();                                     // sync 6
    fft_stage<3>(Z, tid);
    __syncthreads();                                     // sync 7
    fft_stage<4>(Z, tid);
    __syncthreads();                                     // sync 8

    // ---------- magnitudes: conjugate pair {k, 2048-k} unpacked once ----------
    // X_k = (Er+u, Ei+v), X_{2048-k} = (Er-u, v-Ei)
    const float inv_T = 1.f / (float)T_LEN;
    float a0 = -1.f, a1 = -1.f, a2 = -1.f;
    #pragma unroll
    for (int i = 0; i < 4; i++) {
        int k  = 1 + tid + (i << 8);                     // 1..1024
        int pa = fpos(k);
        int pb = fpos(M_LEN - k);
        float ang = (float)k * (-3.14159265358979f / (float)M_LEN);
        float sn, cs; __sincosf(ang, &sn, &cs);
        float2 Za = rdpost(Z, pa), Zb = rdpost(Z, pb);
        float Er = 0.5f * (Za.x + Zb.x), Ei = 0.5f * (Za.y - Zb.y);
        float Or = 0.5f * (Za.y + Zb.y), Oi = 0.5f * (Zb.x - Za.x);
        float u = cs * Or - sn * Oi, vv = cs * Oi + sn * Or;
        float Xr = Er + u, Xi = Ei + vv;
        ins3(a0, a1, a2, sqrtf(Xr * Xr + Xi * Xi));
        if (k != 1024) {
            float Yr = Er - u, Yi = vv - Ei;
            ins3(a0, a1, a2, sqrtf(Yr * Yr + Yi * Yi));
        }
    }
    if (tid == 0) {                                      // Nyquist k=2048
        float2 Z0 = rdpost(Z, 0);
        ins3(a0, a1, a2, fabsf(Z0.x - Z0.y));
    }
    #pragma unroll
    for (int o = 32; o > 0; o >>= 1) {
        float u0 = __shfl_down(a0, o), u1 = __shfl_down(a1, o), u2 = __shfl_down(a2, o);
        ins3(a0, a1, a2, u0); ins3(a0, a1, a2, u1); ins3(a0, a1, a2, u2);
    }
    if (lane == 0) {
        scr[SCR_C_PART + wv * 3 + 0] = a0;
        scr[SCR_C_PART + wv * 3 + 1] = a1;
        scr[SCR_C_PART + wv * 3 + 2] = a2;
    }
    __syncthreads();                                     // sync 9
    if (tid == 0) {
        float t0 = scr[SCR_C_PART], t1 = scr[SCR_C_PART + 1], t2 = scr[SCR_C_PART + 2];
        #pragma unroll
        for (int w = 1; w < NWAVES; w++) {
            ins3(t0, t1, t2, scr[SCR_C_PART + w * 3 + 0]);
            ins3(t0, t1, t2, scr[SCR_C_PART + w * 3 + 1]);
            ins3(t0, t1, t2, scr[SCR_C_PART + w * 3 + 2]);
        }
        float* fp = feats + sid;
        fp[7 * FS] = t0 * inv_T; fp[8 * FS] = t1 * inv_T; fp[9 * FS] = t2 * inv_T;
    }
}

// One 32-lane group per (b, f): coalesced 128-B read + shuffle reduce.
__global__ __launch_bounds__(256)
void ts_reduce_kernel(const float* __restrict__ feats, float* __restrict__ out) {
    const int tid = threadIdx.x;
    const int lane = tid & 63;
    const int wid = blockIdx.x * 4 + (tid >> 6);      // global wave 0..1023
    const int pairidx = wid * 2 + (lane >> 5);        // (b,f) pair 0..2047
    const int b = pairidx >> 4, f = pairidx & 15;
    const int v = lane & 31;
    float val = feats[f * FS + b * V_DIM + v];
    float s = val;
    #pragma unroll
    for (int o = 16; o > 0; o >>= 1) s += __shfl_xor(s, o);
    float m = s * (1.f / V_DIM);
    float d = val - m;
    float q = d * d;
    #pragma unroll
    for (int o = 16; o > 0; o >>= 1) q += __shfl_xor(q, o);
    float sd = sqrtf(q * (1.f / V_DIM));
    if (v == 0) {
        out[b * 32 + f]      = fminf(fmaxf(m,  -5.f), 5.f);
        out[b * 32 + 16 + f] = fminf(fmaxf(sd, -5.f), 5.f);
    }
}

extern "C" void kernel_launch(void* const* d_in, const int* in_sizes, int n_in,
                              void* d_out, int out_size, void* d_ws, size_t ws_size,
                              hipStream_t stream) {
    const float* x = (const float*)d_in[0];
    float* out = (float*)d_out;
    float* feats = (float*)d_ws;   // feature-major [16][4096] = 256 KB

    hipLaunchKernelGGL(ts_feat_kernel, dim3(NSERIES), dim3(NTHREADS), 0, stream,
                       x, feats);
    hipLaunchKernelGGL(ts_reduce_kernel, dim3(256), dim3(256), 0, stream,
                       feats, out);
}